// Round 1
// baseline (301.494 us; speedup 1.0000x reference)
//
#include <hip/hip_runtime.h>
#include <math.h>

#define NEGV (-1e30f)

__device__ __forceinline__ float lae2(float a, float b) {
    float m = fmaxf(a, b);
    return m + __logf(__expf(a - m) + __expf(b - m));
}

__device__ __forceinline__ float lae3(float a, float b, float c) {
    float m = fmaxf(fmaxf(a, b), c);
    return m + __logf(__expf(a - m) + __expf(b - m) + __expf(c - m));
}

// One block per sample n. Threads 0..L-1 own extended position s for BOTH
// label sequences (ctc + ref). All 256 threads cooperatively stage the
// (t, n, :) class row (C=256 floats) into LDS, pipelined 2 steps deep.
__global__ __launch_bounds__(256) void ctc_pair_kernel(
    const float* __restrict__ lp,        // (T, N, C) log-probs
    const int* __restrict__ labels,      // (N, S)
    const int* __restrict__ rlabels,     // (N, S)
    const int* __restrict__ ilen,        // (N,) input lengths
    const int* __restrict__ llen,        // (N,) label lengths
    const int* __restrict__ rlen,        // (N,) ref label lengths
    float* __restrict__ loss,            // (2N,): [0,N) ctc, [N,2N) ref
    int T, int N, int C, int S)
{
    const int n = blockIdx.x;
    const int tid = threadIdx.x;
    const int L = 2 * S + 1;             // 201

    __shared__ float row[4][256];        // staged class rows, depth 4
    __shared__ float al[2][2][204];      // [seq][buf][s+2]; [0],[1] = NEG sentinels

    // per-thread extended label + skip flag (constant over t)
    int e0 = 0, e1 = 0;
    bool k0 = false, k1 = false;
    if (tid < L && (tid & 1)) {
        int j = tid >> 1;
        e0 = labels[n * S + j];
        e1 = rlabels[n * S + j];
        if (tid >= 2) {
            int p0 = labels[n * S + j - 1];
            int p1 = rlabels[n * S + j - 1];
            k0 = (e0 != 0) && (e0 != p0);
            k1 = (e1 != 0) && (e1 != p1);
        }
    }
    const int inlen = ilen[n];

    const size_t stride = (size_t)N * C;
    const float* gp = lp + (size_t)n * C + tid;

    // prologue: rows 0..2 -> LDS, rows 3,4 in flight in registers
    row[0][tid] = gp[0];
    if (T > 1) row[1][tid] = gp[stride];
    if (T > 2) row[2][tid] = gp[2 * stride];
    float rA = (T > 3) ? gp[3 * stride] : 0.f;
    float rB = (T > 4) ? gp[4 * stride] : 0.f;

    if (tid < 2) {
        al[0][0][tid] = NEGV; al[0][1][tid] = NEGV;
        al[1][0][tid] = NEGV; al[1][1][tid] = NEGV;
    }
    __syncthreads();

    // t = 0 init into alpha buffer 0
    float a0 = NEGV, a1 = NEGV;
    if (tid < L) {
        if (tid <= 1) { a0 = row[0][e0]; a1 = row[0][e1]; }
        al[0][0][tid + 2] = a0;
        al[1][0][tid + 2] = a1;
    }
    __syncthreads();

    // one step of the alpha recursion; exactly one barrier per step.
    // rr holds row t+2 (loaded two steps ago); we ds_write it to the LDS slot
    // that will be read at step t+2, then issue the load for row t+4.
    auto step = [&](int t, float& rr) {
        const float* rowt = row[t & 3];
        const int rb = (t - 1) & 1, wb = t & 1;
        if (t + 2 < T) row[(t + 2) & 3][tid] = rr;
        if (t + 4 < T) rr = gp[(size_t)(t + 4) * stride];
        if (tid < L) {
            float p1a = al[0][rb][tid + 1];   // alpha[s-1]
            float p2a = al[0][rb][tid];       // alpha[s-2]
            float p1b = al[1][rb][tid + 1];
            float p2b = al[1][rb][tid];
            float em0 = rowt[e0];
            float em1 = rowt[e1];
            float v0 = lae3(a0, p1a, k0 ? p2a : NEGV) + em0;
            float v1 = lae3(a1, p1b, k1 ? p2b : NEGV) + em1;
            if (t < inlen) { a0 = v0; a1 = v1; }   // freeze past input length
            al[0][wb][tid + 2] = a0;
            al[1][wb][tid + 2] = a1;
        }
        __syncthreads();
    };

    int t = 1;
    for (; t + 1 < T; t += 2) { step(t, rA); step(t + 1, rB); }
    if (t < T) step(t, rA);

    if (tid == 0) {
        const int fb = (T - 1) & 1;
        int l0 = llen[n];
        float hi = al[0][fb][2 * l0 + 2];
        float lo = al[0][fb][2 * l0 + 1];
        loss[n] = -lae2(hi, lo);
        int l1 = rlen[n];
        hi = al[1][fb][2 * l1 + 2];
        lo = al[1][fb][2 * l1 + 1];
        loss[N + n] = -lae2(hi, lo);
    }
}

__global__ __launch_bounds__(256) void ctc_finalize_kernel(
    const float* __restrict__ ws, float* __restrict__ out, int N)
{
    __shared__ float sc[256], sh[256];
    const int i = threadIdx.x;
    float c = 0.f, h = 0.f;
    for (int nn = i; nn < N; nn += 256) {
        float cv = ws[nn];
        float rv = ws[N + nn];
        c += cv;
        float dap = fabsf(1e-6f - cv);
        float dan = fabsf(1e-6f - rv);
        h += fmaxf(dap - dan + 16.0f, 0.f);
    }
    sc[i] = c; sh[i] = h;
    __syncthreads();
    for (int off = 128; off > 0; off >>= 1) {
        if (i < off) { sc[i] += sc[i + off]; sh[i] += sh[i + off]; }
        __syncthreads();
    }
    if (i == 0) out[0] = sc[0] + sh[0] / (float)N;
}

extern "C" void kernel_launch(void* const* d_in, const int* in_sizes, int n_in,
                              void* d_out, int out_size, void* d_ws, size_t ws_size,
                              hipStream_t stream) {
    const float* lp      = (const float*)d_in[0];   // predicts (T,N,C) f32
    const int* labels    = (const int*)d_in[1];     // (N,S)
    const int* rlabels   = (const int*)d_in[2];     // (N,S)
    const int* plen      = (const int*)d_in[3];     // (N,)
    const int* llen      = (const int*)d_in[4];     // (N,)
    const int* rlen      = (const int*)d_in[5];     // (N,)

    const int N = in_sizes[3];
    const int S = in_sizes[1] / N;
    const int C = 256;                              // classes (fixed for this problem)
    const int T = in_sizes[0] / (N * C);

    float* ws = (float*)d_ws;                       // 2N floats of per-seq losses

    ctc_pair_kernel<<<N, 256, 0, stream>>>(lp, labels, rlabels, plen, llen, rlen,
                                           ws, T, N, C, S);
    ctc_finalize_kernel<<<1, 256, 0, stream>>>(ws, (float*)d_out, N);
}

// Round 2
// 269.135 us; speedup vs baseline: 1.1202x; 1.1202x over previous
//
#include <hip/hip_runtime.h>
#include <math.h>

#define NEGV (-1e30f)

__device__ __forceinline__ float lae2(float a, float b) {
    float m = fmaxf(a, b);
    return m + __logf(__expf(a - m) + __expf(b - m));
}

__device__ __forceinline__ float lae3(float a, float b, float c) {
    float m = fmaxf(fmaxf(a, b), c);
    return m + __logf(__expf(a - m) + __expf(b - m) + __expf(c - m));
}

// Raw barrier that does NOT drain vmcnt: LDS writes are made visible
// (lgkmcnt(0)) but global prefetch loads stay in flight across the barrier.
// "memory" clobbers pin LDS accesses on both sides.
__device__ __forceinline__ void barrier_lgkm() {
    asm volatile("s_waitcnt lgkmcnt(0)" ::: "memory");
    __builtin_amdgcn_s_barrier();
    asm volatile("" ::: "memory");
}

// One block per sample n. Threads 0..L-1 own extended position s for BOTH
// label sequences (ctc + ref). All 256 threads cooperatively stage the
// (t, n, :) class row into LDS; global->reg prefetch 4 steps deep survives
// the per-step barrier (no vmcnt drain).
__global__ __launch_bounds__(256) void ctc_pair_kernel(
    const float* __restrict__ lp,        // (T, N, C) log-probs
    const int* __restrict__ labels,      // (N, S)
    const int* __restrict__ rlabels,     // (N, S)
    const int* __restrict__ ilen,        // (N,)
    const int* __restrict__ llen,        // (N,)
    const int* __restrict__ rlen,        // (N,)
    float* __restrict__ loss,            // (2N,)
    int T, int N, int C, int S)
{
    const int n = blockIdx.x;
    const int tid = threadIdx.x;
    const int L = 2 * S + 1;             // 201

    __shared__ float row[2][256];        // staged class rows, ring depth 2
    __shared__ float al[2][2][204];      // [seq][buf][s+2]; [0],[1] = NEG sentinels

    // per-thread extended label + skip flag (constant over t)
    int e0 = 0, e1 = 0;
    bool k0 = false, k1 = false;
    if (tid < L && (tid & 1)) {
        int j = tid >> 1;
        e0 = labels[n * S + j];
        e1 = rlabels[n * S + j];
        if (tid >= 2) {
            int p0 = labels[n * S + j - 1];
            int p1 = rlabels[n * S + j - 1];
            k0 = (e0 != 0) && (e0 != p0);
            k1 = (e1 != 0) && (e1 != p1);
        }
    }
    const int inlen = ilen[n];

    const size_t stride = (size_t)N * C;
    const float* gp = lp + (size_t)n * C + tid;
    const int Tm1 = T - 1;

    // prologue: rows 0,1 -> LDS direct; rows 2..5 in flight in registers
    row[0][tid] = gp[0];
    if (T > 1) row[1][tid] = gp[stride];
    float r0 = (T > 2) ? gp[2 * stride] : 0.f;
    float r1 = (T > 3) ? gp[3 * stride] : 0.f;
    float r2 = (T > 4) ? gp[4 * stride] : 0.f;
    float r3 = (T > 5) ? gp[5 * stride] : 0.f;

    if (tid < 2) {
        al[0][0][tid] = NEGV; al[0][1][tid] = NEGV;
        al[1][0][tid] = NEGV; al[1][1][tid] = NEGV;
    }
    __syncthreads();   // full drain once (init needs row 0 in LDS)

    // t = 0 init into alpha buffer 0
    float a0 = NEGV, a1 = NEGV;
    if (tid < L) {
        if (tid <= 1) { a0 = row[0][e0]; a1 = row[0][e1]; }
        al[0][0][tid + 2] = a0;
        al[1][0][tid + 2] = a1;
    }
    __syncthreads();

    // step t: read row[t&1]; ds_write row t+1 from rr (loaded 4 steps ago);
    // refill rr with row t+5 (clamped). Exactly one lgkm-only barrier/step.
    auto step = [&](int t, float& rr) {
        const float* rowt = row[t & 1];
        const int rb = (t - 1) & 1, wb = t & 1;
        row[(t + 1) & 1][tid] = rr;                    // vmcnt wait lands here only
        int tn = t + 5; if (tn > Tm1) tn = Tm1;
        rr = gp[(size_t)tn * stride];                  // stays in flight across barriers
        if (tid < L) {
            float p1a = al[0][rb][tid + 1];   // alpha[s-1]
            float p2a = al[0][rb][tid];       // alpha[s-2]
            float p1b = al[1][rb][tid + 1];
            float p2b = al[1][rb][tid];
            float em0 = rowt[e0];
            float em1 = rowt[e1];
            float v0 = lae3(a0, p1a, k0 ? p2a : NEGV) + em0;
            float v1 = lae3(a1, p1b, k1 ? p2b : NEGV) + em1;
            if (t < inlen) { a0 = v0; a1 = v1; }   // freeze past input length
            al[0][wb][tid + 2] = a0;
            al[1][wb][tid + 2] = a1;
        }
        barrier_lgkm();
    };

    int t = 1;
    for (; t + 3 < T; t += 4) {
        step(t + 0, r0);
        step(t + 1, r1);
        step(t + 2, r2);
        step(t + 3, r3);
    }
    // tail (<=3 steps); reg rotation restarts at r0 after each full unroll
    if (t < T) { step(t, r0); ++t; }
    if (t < T) { step(t, r1); ++t; }
    if (t < T) { step(t, r2); ++t; }

    if (tid == 0) {
        const int fb = (T - 1) & 1;
        int l0 = llen[n];
        float hi = al[0][fb][2 * l0 + 2];
        float lo = al[0][fb][2 * l0 + 1];
        loss[n] = -lae2(hi, lo);
        int l1 = rlen[n];
        hi = al[1][fb][2 * l1 + 2];
        lo = al[1][fb][2 * l1 + 1];
        loss[N + n] = -lae2(hi, lo);
    }
}

__global__ __launch_bounds__(256) void ctc_finalize_kernel(
    const float* __restrict__ ws, float* __restrict__ out, int N)
{
    __shared__ float sc[256], sh[256];
    const int i = threadIdx.x;
    float c = 0.f, h = 0.f;
    for (int nn = i; nn < N; nn += 256) {
        float cv = ws[nn];
        float rv = ws[N + nn];
        c += cv;
        float dap = fabsf(1e-6f - cv);
        float dan = fabsf(1e-6f - rv);
        h += fmaxf(dap - dan + 16.0f, 0.f);
    }
    sc[i] = c; sh[i] = h;
    __syncthreads();
    for (int off = 128; off > 0; off >>= 1) {
        if (i < off) { sc[i] += sc[i + off]; sh[i] += sh[i + off]; }
        __syncthreads();
    }
    if (i == 0) out[0] = sc[0] + sh[0] / (float)N;
}

extern "C" void kernel_launch(void* const* d_in, const int* in_sizes, int n_in,
                              void* d_out, int out_size, void* d_ws, size_t ws_size,
                              hipStream_t stream) {
    const float* lp      = (const float*)d_in[0];   // predicts (T,N,C) f32
    const int* labels    = (const int*)d_in[1];     // (N,S)
    const int* rlabels   = (const int*)d_in[2];     // (N,S)
    const int* plen      = (const int*)d_in[3];     // (N,)
    const int* llen      = (const int*)d_in[4];     // (N,)
    const int* rlen      = (const int*)d_in[5];     // (N,)

    const int N = in_sizes[3];
    const int S = in_sizes[1] / N;
    const int C = 256;
    const int T = in_sizes[0] / (N * C);

    float* ws = (float*)d_ws;                       // 2N floats of per-seq losses

    ctc_pair_kernel<<<N, 256, 0, stream>>>(lp, labels, rlabels, plen, llen, rlen,
                                           ws, T, N, C, S);
    ctc_finalize_kernel<<<1, 256, 0, stream>>>(ws, (float*)d_out, N);
}